// Round 20
// baseline (146.205 us; speedup 1.0000x reference)
//
#include <hip/hip_runtime.h>
#include <hip/hip_fp16.h>
#include <math.h>

#define FIN 256
#define HID 128
#define NCLS 40
#define ZPB 64   // fp8 Z row stride in bytes (one cache line)
#define BKT_SHIFT 9
#define BKT_SZ 512
#define CHUNK 2048
#define CAP 12288   // bucket region capacity (mean 8192, sd ~90 -> 45 sd headroom)

typedef __attribute__((ext_vector_type(8))) short short8_t;
typedef __attribute__((ext_vector_type(8))) _Float16 half8_t;
typedef __attribute__((ext_vector_type(4))) float f32x4;
typedef __attribute__((ext_vector_type(2))) float f32x2;

static __device__ __forceinline__ ushort f2bf(float f) {
    unsigned u = __float_as_uint(f);
    u += 0x7FFF + ((u >> 16) & 1);
    return (ushort)(u >> 16);
}

// packed edge (eew): src (17 bits) << 15 | top-15-bits-of-fp32-weight
static __device__ __forceinline__ unsigned pack_ew(int s, float w) {
    return ((unsigned)s << 15) | (__float_as_uint(w) >> 17);
}

// H-path layout permutation: position p of an H row holds feature
// pi(p) = (p&7)*16 + (p>>3)  (lets gemm1/agg1 store MFMA fragments directly)

// ---------------- prep: zero bucket cursors + ticket + convert W1/W2 ----------------

__global__ void k_prep(int* __restrict__ bcur, const float* __restrict__ W1,
                       ushort* __restrict__ Wt, const float* __restrict__ W2,
                       __half* __restrict__ W2t, int nbk) {
    int i = blockIdx.x * 256 + threadIdx.x;
    if (i <= nbk) bcur[i] = 0;   // bcur[nbk] doubles as the global base ticket
    if (i < FIN * HID) {
        int c = i >> 8, k = i & 255;
        Wt[i] = f2bf(W1[(size_t)k * HID + c]);
    }
    if (i < 48 * HID) {
        int c = i >> 7, p = i & 127;
        int k = (p & 7) * 16 + (p >> 3);   // permuted k-dimension to match H layout
        W2t[i] = __float2half((c < NCLS) ? W2[(size_t)k * NCLS + c] : 0.f);
    }
}

// ---------------- fused: bucketize (blockIdx%3==0) + GEMM1 (rest), interleaved ----------------

__global__ __launch_bounds__(256) void k_g1bkt(const float* __restrict__ X,
                                               const ushort* __restrict__ Wt,
                                               unsigned char* __restrict__ H8, int M,
                                               const int* __restrict__ src,
                                               const int* __restrict__ dst, int E,
                                               int* __restrict__ bcur,
                                               unsigned* __restrict__ ebkt,
                                               int nbk, int nbkb) {
    __shared__ uint4 wlds[64 * 32];   // 32 KB: W half-tile OR bucketize scratch
    int tid = threadIdx.x;
    int b = (int)blockIdx.x;
    bool is_bkt = ((b % 3) == 0) && (b / 3 < nbkb);

    if (is_bkt) {
        int bkb = b / 3;
        int* hist  = (int*)wlds;
        int* scanb = hist + 256;
        int* base  = scanb + 256;
        int* gbase = base + 256;
        unsigned* stage = (unsigned*)(gbase + 256);
        unsigned char* sbk = (unsigned char*)(stage + CHUNK);
        int e0 = bkb * CHUNK;
        int cntc = min(CHUNK, E - e0);
        hist[tid] = 0;
        __syncthreads();

        int s_[8], d_[8], bk_[8], rk_[8];
#pragma unroll
        for (int i = 0; i < 8; i++) {
            int j = tid + i * 256;
            if (j < cntc) {
                int s = src[e0 + j], d = dst[e0 + j];
                s_[i] = s; d_[i] = d;
                bk_[i] = d >> BKT_SHIFT;
                rk_[i] = atomicAdd(&hist[bk_[i]], 1);
            } else {
                bk_[i] = -1;
            }
        }
        __syncthreads();

        scanb[tid] = hist[tid];
        __syncthreads();
        for (int o = 1; o < 256; o <<= 1) {
            int u = (tid >= o) ? scanb[tid - o] : 0;
            __syncthreads();
            scanb[tid] += u;
            __syncthreads();
        }
        base[tid] = scanb[tid] - hist[tid];
        if (tid < nbk && hist[tid] > 0) gbase[tid] = atomicAdd(&bcur[tid], hist[tid]);
        __syncthreads();

#pragma unroll
        for (int i = 0; i < 8; i++) {
            if (bk_[i] >= 0) {
                int p = base[bk_[i]] + rk_[i];
                stage[p] = ((unsigned)s_[i] << 9) | ((unsigned)d_[i] & 511u);
                sbk[p] = (unsigned char)bk_[i];
            }
        }
        __syncthreads();

#pragma unroll
        for (int i = 0; i < 8; i++) {
            int j = tid + i * 256;
            if (j < cntc) {
                int bk = sbk[j];
                ebkt[(size_t)bk * CAP + gbase[bk] + (j - base[bk])] = stage[j];
            }
        }
        return;
    }

    // ---- gemm1 body ----
    int bid = b - b / 3 - ((b % 3) ? 1 : 0);
    if (b % 3 == 0) bid = nbkb * 2 + (b / 3 - nbkb);
    int wid = tid >> 6, lane = tid & 63;
    int q = lane & 15, kg = lane >> 4;
    int grow_in = bid * 64 + wid * 16 + q;
    int lrow = min(grow_in, M - 1);
    const float* xr = X + (size_t)lrow * FIN;

    // issue all 16 X loads (stay in flight while W half-0 loads issue)
    float4 xf0[8], xf1[8];
#pragma unroll
    for (int kt = 0; kt < 8; kt++) {
        int k0 = kt * 32 + kg * 8;
        xf0[kt] = *(const float4*)(xr + k0);
        xf1[kt] = *(const float4*)(xr + k0 + 4);
    }

    const uint4* wg = (const uint4*)Wt;
    // stage W half 0 while X loads are in flight (vmcnt drain covers both)
#pragma unroll
    for (int i = 0; i < 8; i++) {
        int e = tid + i * 256;
        int lc = e >> 5, ch = e & 31;
        wlds[lc * 32 + (ch ^ (lc & 7))] = wg[e];
    }

    // convert X -> bf16 a-fragments (data already resident, no wait)
    short8_t a[8];
#pragma unroll
    for (int kt = 0; kt < 8; kt++) {
        unsigned r0, r1, r2, r3;
        asm("v_cvt_pk_bf16_f32 %0, %1, %2" : "=v"(r0) : "v"(xf0[kt].x), "v"(xf0[kt].y));
        asm("v_cvt_pk_bf16_f32 %0, %1, %2" : "=v"(r1) : "v"(xf0[kt].z), "v"(xf0[kt].w));
        asm("v_cvt_pk_bf16_f32 %0, %1, %2" : "=v"(r2) : "v"(xf1[kt].x), "v"(xf1[kt].y));
        asm("v_cvt_pk_bf16_f32 %0, %1, %2" : "=v"(r3) : "v"(xf1[kt].z), "v"(xf1[kt].w));
        union { uint4 u; short8_t s; } cv;
        cv.u = make_uint4(r0, r1, r2, r3);
        a[kt] = cv.s;
    }

    f32x4 accA[4], accB[4];
#pragma unroll
    for (int c = 0; c < 4; c++) {
        accA[c] = (f32x4){0.f, 0.f, 0.f, 0.f};
        accB[c] = (f32x4){0.f, 0.f, 0.f, 0.f};
    }

    __syncthreads();
    // MFMA half 0
#pragma unroll
    for (int kt = 0; kt < 8; kt++) {
        int ch = kt * 4 + kg;
#pragma unroll
        for (int c = 0; c < 4; c++) {
            int lc = c * 16 + q;
            short8_t bfr = *(const short8_t*)&wlds[lc * 32 + (ch ^ (lc & 7))];
            accA[c] = __builtin_amdgcn_mfma_f32_16x16x32_bf16(a[kt], bfr, accA[c], 0, 0, 0);
        }
    }
    __syncthreads();
    // stage + MFMA half 1
#pragma unroll
    for (int i = 0; i < 8; i++) {
        int e = tid + i * 256;
        int lc = e >> 5, ch = e & 31;
        wlds[lc * 32 + (ch ^ (lc & 7))] = wg[2048 + e];
    }
    __syncthreads();
#pragma unroll
    for (int kt = 0; kt < 8; kt++) {
        int ch = kt * 4 + kg;
#pragma unroll
        for (int c = 0; c < 4; c++) {
            int lc = c * 16 + q;
            short8_t bfr = *(const short8_t*)&wlds[lc * 32 + (ch ^ (lc & 7))];
            accB[c] = __builtin_amdgcn_mfma_f32_16x16x32_bf16(a[kt], bfr, accB[c], 0, 0, 0);
        }
    }

#pragma unroll
    for (int i = 0; i < 4; i++) {
        int r = bid * 64 + wid * 16 + kg * 4 + i;
        if (r < M) {
            int lo = 0, hi = 0;
            lo = __builtin_amdgcn_cvt_pk_fp8_f32(accA[0][i], accA[1][i], lo, false);
            lo = __builtin_amdgcn_cvt_pk_fp8_f32(accA[2][i], accA[3][i], lo, true);
            hi = __builtin_amdgcn_cvt_pk_fp8_f32(accB[0][i], accB[1][i], hi, false);
            hi = __builtin_amdgcn_cvt_pk_fp8_f32(accB[2][i], accB[3][i], hi, true);
            *(uint2*)(H8 + (size_t)r * HID + q * 8) = make_uint2((unsigned)lo, (unsigned)hi);
        }
    }
}

// ---------------- per-bucket LDS histogram + scan -> off, cnt, dinv ----------------

__global__ __launch_bounds__(512) void k_cnt(const unsigned* __restrict__ ebkt,
                                             int* __restrict__ bcur, int nbk,
                                             int* __restrict__ off, int* __restrict__ cnt,
                                             float* __restrict__ dinv, int n) {
    __shared__ int lcnt[BKT_SZ];
    __shared__ int lofs[BKT_SZ];
    __shared__ int lbase;
    int b = blockIdx.x, t = threadIdx.x;
    int n0 = b << BKT_SHIFT;
    lcnt[t] = 0;
    __syncthreads();
    int sz = bcur[b];
    const unsigned* ep = ebkt + (size_t)b * CAP;
    for (int e = t; e < sz; e += 512) atomicAdd(&lcnt[ep[e] & 511u], 1);
    __syncthreads();
    if (t == 0) lbase = atomicAdd(&bcur[nbk], sz);
    lofs[t] = lcnt[t];
    __syncthreads();
    for (int o = 1; o < 512; o <<= 1) {
        int u = (t >= o) ? lofs[t - o] : 0;
        __syncthreads();
        lofs[t] += u;
        __syncthreads();
    }
    int node = n0 + t;
    if (node < n) {
        int c = lcnt[t];
        off[node] = lbase + lofs[t] - c;
        cnt[node] = c;
        dinv[node] = rsqrtf((float)(c + 1));
    }
}

// ---------------- per-bucket placement: pack (src, weight) via LDS cursors ----------------

__global__ __launch_bounds__(512) void k_place(const unsigned* __restrict__ ebkt,
                                               const int* __restrict__ bcur,
                                               const int* __restrict__ off,
                                               const float* __restrict__ dinv,
                                               unsigned* __restrict__ eew, int n) {
    __shared__ int curx[BKT_SZ];
    __shared__ float ldin[BKT_SZ];
    int b = blockIdx.x, t = threadIdx.x;
    int n0 = b << BKT_SHIFT;
    int node = n0 + t;
    if (node < n) {
        curx[t] = off[node];
        ldin[t] = dinv[node];
    }
    __syncthreads();
    int sz = bcur[b];
    const unsigned* ep = ebkt + (size_t)b * CAP;
    for (int e = t; e < sz; e += 512) {
        unsigned ed = ep[e];
        int s = (int)(ed >> 9), dl = (int)(ed & 511u);
        float w = dinv[s] * ldin[dl];
        int pos = atomicAdd(&curx[dl], 1);
        eew[pos] = pack_ew(s, w);
    }
}

// ---------------- agg1 + GEMM2 fused: Z8 = fp8( relu(b1 + agg(H8)) @ W2 ) ----------------

__global__ __launch_bounds__(256) void k_agg1(const unsigned char* __restrict__ H8,
                                              const unsigned* __restrict__ eew,
                                              const int* __restrict__ off,
                                              const int* __restrict__ cnt,
                                              const float* __restrict__ dinv,
                                              const float* __restrict__ b1,
                                              const __half* __restrict__ W2t,
                                              unsigned char* __restrict__ Z8, int n) {
    __shared__ __half h2s[16][136];   // padded: 272 B row stride (2-way bank alias)
    int tid = threadIdx.x;
    int g = tid >> 4, q = tid & 15;
    int node = blockIdx.x * 16 + g;
    int nodec = min(node, n - 1);     // clamp; padding rows never stored
    float di = dinv[nodec];
    int start = off[nodec], ne = cnt[nodec];

    float acc[8];
    {
        uint2 v = *(const uint2*)(H8 + (size_t)nodec * HID + q * 8);
        float wv = di * di;
        f32x2 f;
        f = __builtin_amdgcn_cvt_pk_f32_fp8((int)v.x, false);
        acc[0] = f[0] * wv; acc[1] = f[1] * wv;
        f = __builtin_amdgcn_cvt_pk_f32_fp8((int)v.x, true);
        acc[2] = f[0] * wv; acc[3] = f[1] * wv;
        f = __builtin_amdgcn_cvt_pk_f32_fp8((int)v.y, false);
        acc[4] = f[0] * wv; acc[5] = f[1] * wv;
        f = __builtin_amdgcn_cvt_pk_f32_fp8((int)v.y, true);
        acc[6] = f[0] * wv; acc[7] = f[1] * wv;
    }

#pragma unroll 8
    for (int j = 0; j < ne; ++j) {
        unsigned u = eew[start + j];          // group-uniform broadcast load
        int s = (int)(u >> 15);
        float wv = __uint_as_float((u & 0x7FFFu) << 17);
        uint2 v = *(const uint2*)(H8 + (size_t)s * HID + q * 8);
        f32x2 f;
        f = __builtin_amdgcn_cvt_pk_f32_fp8((int)v.x, false);
        acc[0] = fmaf(f[0], wv, acc[0]); acc[1] = fmaf(f[1], wv, acc[1]);
        f = __builtin_amdgcn_cvt_pk_f32_fp8((int)v.x, true);
        acc[2] = fmaf(f[0], wv, acc[2]); acc[3] = fmaf(f[1], wv, acc[3]);
        f = __builtin_amdgcn_cvt_pk_f32_fp8((int)v.y, false);
        acc[4] = fmaf(f[0], wv, acc[4]); acc[5] = fmaf(f[1], wv, acc[5]);
        f = __builtin_amdgcn_cvt_pk_f32_fp8((int)v.y, true);
        acc[6] = fmaf(f[0], wv, acc[6]); acc[7] = fmaf(f[1], wv, acc[7]);
    }

    float r[8];
#pragma unroll
    for (int i = 0; i < 8; i++) r[i] = fmaxf(acc[i] + b1[i * 16 + q], 0.f);  // feature i*16+q
    __half2 p0 = __floats2half2_rn(r[0], r[1]);
    __half2 p1 = __floats2half2_rn(r[2], r[3]);
    __half2 p2 = __floats2half2_rn(r[4], r[5]);
    __half2 p3 = __floats2half2_rn(r[6], r[7]);
    uint4 o4;
    o4.x = *(unsigned*)&p0; o4.y = *(unsigned*)&p1;
    o4.z = *(unsigned*)&p2; o4.w = *(unsigned*)&p3;
    *(uint4*)&h2s[g][q * 8] = o4;   // permuted fp16 row into LDS
    __syncthreads();

    // ---- gemm2 epilogue (wave 0 only): 16 nodes x 40 classes via MFMA fp16 ----
    if (tid < 64) {
        int qq = tid & 15, kg = tid >> 4;
        half8_t a[4];
#pragma unroll
        for (int kt = 0; kt < 4; kt++)
            a[kt] = *(const half8_t*)&h2s[qq][kt * 32 + kg * 8];

        f32x4 zacc[3];
#pragma unroll
        for (int c = 0; c < 3; c++) zacc[c] = (f32x4){0.f, 0.f, 0.f, 0.f};

#pragma unroll
        for (int c = 0; c < 3; c++) {
            const __half* wc = W2t + (size_t)(c * 16 + qq) * HID + kg * 8;
#pragma unroll
            for (int kt = 0; kt < 4; kt++) {
                half8_t bfr = *(const half8_t*)(wc + kt * 32);
                zacc[c] = __builtin_amdgcn_mfma_f32_16x16x32_f16(a[kt], bfr, zacc[c], 0, 0, 0);
            }
        }

        int rbase = blockIdx.x * 16 + kg * 4;
#pragma unroll
        for (int c = 0; c < 3; c++) {
            int col = c * 16 + qq;
            if (col < NCLS) {
#pragma unroll
                for (int i = 0; i < 4; i++) {
                    int rr = rbase + i;
                    if (rr < n) {
                        int p = __builtin_amdgcn_cvt_pk_fp8_f32(zacc[c][i], zacc[c][i], 0, false);
                        Z8[(size_t)rr * ZPB + col] = (unsigned char)(p & 0xff);
                    }
                }
            }
        }
    }
}

// ---------------- agg2 + bias + log_softmax (fp8 Z, 1 line/gather) ----------------

__global__ __launch_bounds__(256) void k_agg2(const unsigned char* __restrict__ Z8,
                                              const unsigned* __restrict__ eew,
                                              const int* __restrict__ off,
                                              const int* __restrict__ cnt,
                                              const float* __restrict__ dinv,
                                              const float* __restrict__ b2,
                                              float* __restrict__ Out, int n) {
    int tid = threadIdx.x;
    int node = blockIdx.x * 32 + (tid >> 3);
    int l = tid & 7;
    if (node >= n) return;
    float di = dinv[node];
    int start = off[node], ne = cnt[node];

    float acc[8];
    {
        uint2 v = *(const uint2*)(Z8 + (size_t)node * ZPB + l * 8);
        float wv = di * di;
        f32x2 f;
        f = __builtin_amdgcn_cvt_pk_f32_fp8((int)v.x, false);
        acc[0] = f[0] * wv; acc[1] = f[1] * wv;
        f = __builtin_amdgcn_cvt_pk_f32_fp8((int)v.x, true);
        acc[2] = f[0] * wv; acc[3] = f[1] * wv;
        f = __builtin_amdgcn_cvt_pk_f32_fp8((int)v.y, false);
        acc[4] = f[0] * wv; acc[5] = f[1] * wv;
        f = __builtin_amdgcn_cvt_pk_f32_fp8((int)v.y, true);
        acc[6] = f[0] * wv; acc[7] = f[1] * wv;
    }

#pragma unroll 8
    for (int j = 0; j < ne; ++j) {
        unsigned u = eew[start + j];          // group-uniform broadcast load
        int s = (int)(u >> 15);
        float wv = __uint_as_float((u & 0x7FFFu) << 17);
        uint2 v = *(const uint2*)(Z8 + (size_t)s * ZPB + l * 8);
        f32x2 f;
        f = __builtin_amdgcn_cvt_pk_f32_fp8((int)v.x, false);
        acc[0] = fmaf(f[0], wv, acc[0]); acc[1] = fmaf(f[1], wv, acc[1]);
        f = __builtin_amdgcn_cvt_pk_f32_fp8((int)v.x, true);
        acc[2] = fmaf(f[0], wv, acc[2]); acc[3] = fmaf(f[1], wv, acc[3]);
        f = __builtin_amdgcn_cvt_pk_f32_fp8((int)v.y, false);
        acc[4] = fmaf(f[0], wv, acc[4]); acc[5] = fmaf(f[1], wv, acc[5]);
        f = __builtin_amdgcn_cvt_pk_f32_fp8((int)v.y, true);
        acc[6] = fmaf(f[0], wv, acc[6]); acc[7] = fmaf(f[1], wv, acc[7]);
    }

    bool valid = (l < 5);
    float v[8];
    float m = -INFINITY;
#pragma unroll
    for (int i = 0; i < 8; i++) {
        v[i] = valid ? acc[i] + b2[l * 8 + i] : -INFINITY;
        m = fmaxf(m, v[i]);
    }
#pragma unroll
    for (int o = 1; o <= 4; o <<= 1) m = fmaxf(m, __shfl_xor(m, o));
    float ssum = 0.f;
#pragma unroll
    for (int i = 0; i < 8; i++)
        if (valid) ssum += __expf(v[i] - m);
#pragma unroll
    for (int o = 1; o <= 4; o <<= 1) ssum += __shfl_xor(ssum, o);
    float lse = m + logf(ssum);

    if (valid) {
        float4 w0 = make_float4(v[0] - lse, v[1] - lse, v[2] - lse, v[3] - lse);
        float4 w1 = make_float4(v[4] - lse, v[5] - lse, v[6] - lse, v[7] - lse);
        float* op = Out + (size_t)node * NCLS + l * 8;
        *(float4*)op = w0;
        *(float4*)(op + 4) = w1;
    }
}

// ---------------- launch ----------------

extern "C" void kernel_launch(void* const* d_in, const int* in_sizes, int n_in,
                              void* d_out, int out_size, void* d_ws, size_t ws_size,
                              hipStream_t stream) {
    const float* x  = (const float*)d_in[0];
    const int* ei   = (const int*)d_in[1];
    const float* W1 = (const float*)d_in[2];
    const float* b1 = (const float*)d_in[3];
    const float* W2 = (const float*)d_in[4];
    const float* b2 = (const float*)d_in[5];
    float* out = (float*)d_out;

    const int n = in_sizes[0] / FIN;   // 100000
    const int E = in_sizes[1] / 2;     // 1600000
    const int* src = ei;
    const int* dst = ei + E;
    const int nbk = (n + BKT_SZ - 1) >> BKT_SHIFT;  // 196

    char* w = (char*)d_ws;
    auto alloc = [&](size_t bytes) {
        char* p = w;
        w += (bytes + 255) & ~(size_t)255;
        return p;
    };
    int* off     = (int*)alloc((size_t)n * 4);
    int* cnt     = (int*)alloc((size_t)n * 4);
    float* dinv  = (float*)alloc((size_t)n * 4);
    int* bcur    = (int*)alloc((size_t)(nbk + 1) * 4);  // +1: global base ticket
    unsigned* ebkt = (unsigned*)alloc((size_t)nbk * CAP * 4);
    unsigned* eew  = (unsigned*)alloc((size_t)E * 4);
    ushort* wt   = (ushort*)alloc((size_t)FIN * HID * 2);
    __half* w2t  = (__half*)alloc((size_t)48 * HID * 2);
    unsigned char* H8 = (unsigned char*)alloc((size_t)n * HID);
    unsigned char* Z8 = (unsigned char*)alloc((size_t)n * ZPB);

    const int nbkb = (E + CHUNK - 1) / CHUNK;        // bucketize blocks (782)
    const int g1b = (n + 63) / 64;                   // gemm1 blocks (1563)

    // prep: zero bucket cursors + ticket + convert both weight matrices
    k_prep<<<(FIN * HID) / 256, 256, 0, stream>>>(bcur, W1, wt, W2, w2t, nbk);

    // fused + interleaved: bucketize co-scheduled with half-tiled gemm1
    k_g1bkt<<<nbkb + g1b, 256, 0, stream>>>(x, wt, H8, n, src, dst, E, bcur, ebkt, nbk, nbkb);

    // CSR finalize, bucket-local
    k_cnt<<<nbk, 512, 0, stream>>>(ebkt, bcur, nbk, off, cnt, dinv, n);
    k_place<<<nbk, 512, 0, stream>>>(ebkt, bcur, off, dinv, eew, n);

    // layer 1 aggregation + fused GEMM2
    k_agg1<<<(n + 15) / 16, 256, 0, stream>>>(H8, eew, off, cnt, dinv, b1, w2t, Z8, n);

    // layer 2 aggregation + log_softmax
    k_agg2<<<(n + 31) / 32, 256, 0, stream>>>(Z8, eew, off, cnt, dinv, b2, out, n);
}

// Round 21
// 136.997 us; speedup vs baseline: 1.0672x; 1.0672x over previous
//
#include <hip/hip_runtime.h>
#include <hip/hip_fp16.h>
#include <math.h>

#define FIN 256
#define HID 128
#define NCLS 40
#define ZPB 64   // fp8 Z row stride in bytes (one cache line)
#define BKT_SHIFT 9
#define BKT_SZ 512
#define CHUNK 2048
#define CAP 12288   // bucket region capacity (mean 8192, sd ~90 -> 45 sd headroom)

typedef __attribute__((ext_vector_type(8))) short short8_t;
typedef __attribute__((ext_vector_type(8))) _Float16 half8_t;
typedef __attribute__((ext_vector_type(4))) float f32x4;
typedef __attribute__((ext_vector_type(2))) float f32x2;

static __device__ __forceinline__ ushort f2bf(float f) {
    unsigned u = __float_as_uint(f);
    u += 0x7FFF + ((u >> 16) & 1);
    return (ushort)(u >> 16);
}

// packed edge (eew): src (17 bits) << 15 | top-15-bits-of-fp32-weight
static __device__ __forceinline__ unsigned pack_ew(int s, float w) {
    return ((unsigned)s << 15) | (__float_as_uint(w) >> 17);
}

// H-path layout permutation: position p of an H row holds feature
// pi(p) = (p&7)*16 + (p>>3)  (lets gemm1/agg1 store MFMA fragments directly)

// ---------------- prep: zero bucket cursors + ticket + convert W1/W2 ----------------

__global__ void k_prep(int* __restrict__ bcur, const float* __restrict__ W1,
                       ushort* __restrict__ Wt, const float* __restrict__ W2,
                       __half* __restrict__ W2t, int nbk) {
    int i = blockIdx.x * 256 + threadIdx.x;
    if (i <= nbk) bcur[i] = 0;   // bcur[nbk] doubles as the global base ticket
    if (i < FIN * HID) {
        int c = i >> 8, k = i & 255;
        Wt[i] = f2bf(W1[(size_t)k * HID + c]);
    }
    if (i < 48 * HID) {
        int c = i >> 7, p = i & 127;
        int k = (p & 7) * 16 + (p >> 3);   // permuted k-dimension to match H layout
        W2t[i] = __float2half((c < NCLS) ? W2[(size_t)k * NCLS + c] : 0.f);
    }
}

// ---------------- fused: bucketize (blockIdx%3==0) + GEMM1 (rest), interleaved ----------------

__global__ __launch_bounds__(256) void k_g1bkt(const float* __restrict__ X,
                                               const ushort* __restrict__ Wt,
                                               unsigned char* __restrict__ H8, int M,
                                               const int* __restrict__ src,
                                               const int* __restrict__ dst, int E,
                                               int* __restrict__ bcur,
                                               unsigned* __restrict__ ebkt,
                                               int nbk, int nbkb) {
    __shared__ uint4 wlds[64 * 32];   // 32 KB: W half-tile OR bucketize scratch
    int tid = threadIdx.x;
    int b = (int)blockIdx.x;
    bool is_bkt = ((b % 3) == 0) && (b / 3 < nbkb);

    if (is_bkt) {
        int bkb = b / 3;
        int* hist  = (int*)wlds;
        int* scanb = hist + 256;
        int* base  = scanb + 256;
        int* gbase = base + 256;
        unsigned* stage = (unsigned*)(gbase + 256);
        unsigned char* sbk = (unsigned char*)(stage + CHUNK);
        int e0 = bkb * CHUNK;
        int cntc = min(CHUNK, E - e0);
        hist[tid] = 0;
        __syncthreads();

        int s_[8], d_[8], bk_[8], rk_[8];
#pragma unroll
        for (int i = 0; i < 8; i++) {
            int j = tid + i * 256;
            if (j < cntc) {
                int s = src[e0 + j], d = dst[e0 + j];
                s_[i] = s; d_[i] = d;
                bk_[i] = d >> BKT_SHIFT;
                rk_[i] = atomicAdd(&hist[bk_[i]], 1);
            } else {
                bk_[i] = -1;
            }
        }
        __syncthreads();

        scanb[tid] = hist[tid];
        __syncthreads();
        for (int o = 1; o < 256; o <<= 1) {
            int u = (tid >= o) ? scanb[tid - o] : 0;
            __syncthreads();
            scanb[tid] += u;
            __syncthreads();
        }
        base[tid] = scanb[tid] - hist[tid];
        if (tid < nbk && hist[tid] > 0) gbase[tid] = atomicAdd(&bcur[tid], hist[tid]);
        __syncthreads();

#pragma unroll
        for (int i = 0; i < 8; i++) {
            if (bk_[i] >= 0) {
                int p = base[bk_[i]] + rk_[i];
                stage[p] = ((unsigned)s_[i] << 9) | ((unsigned)d_[i] & 511u);
                sbk[p] = (unsigned char)bk_[i];
            }
        }
        __syncthreads();

#pragma unroll
        for (int i = 0; i < 8; i++) {
            int j = tid + i * 256;
            if (j < cntc) {
                int bk = sbk[j];
                ebkt[(size_t)bk * CAP + gbase[bk] + (j - base[bk])] = stage[j];
            }
        }
        return;
    }

    // ---- gemm1 body ----
    int bid = b - b / 3 - ((b % 3) ? 1 : 0);
    if (b % 3 == 0) bid = nbkb * 2 + (b / 3 - nbkb);
    int wid = tid >> 6, lane = tid & 63;
    int q = lane & 15, kg = lane >> 4;
    int grow_in = bid * 64 + wid * 16 + q;
    int lrow = min(grow_in, M - 1);
    const float* xr = X + (size_t)lrow * FIN;

    float4 xf0[8], xf1[8];
#pragma unroll
    for (int kt = 0; kt < 8; kt++) {
        int k0 = kt * 32 + kg * 8;
        xf0[kt] = *(const float4*)(xr + k0);
        xf1[kt] = *(const float4*)(xr + k0 + 4);
    }

    short8_t a[8];
#pragma unroll
    for (int kt = 0; kt < 8; kt++) {
        unsigned r0, r1, r2, r3;
        asm("v_cvt_pk_bf16_f32 %0, %1, %2" : "=v"(r0) : "v"(xf0[kt].x), "v"(xf0[kt].y));
        asm("v_cvt_pk_bf16_f32 %0, %1, %2" : "=v"(r1) : "v"(xf0[kt].z), "v"(xf0[kt].w));
        asm("v_cvt_pk_bf16_f32 %0, %1, %2" : "=v"(r2) : "v"(xf1[kt].x), "v"(xf1[kt].y));
        asm("v_cvt_pk_bf16_f32 %0, %1, %2" : "=v"(r3) : "v"(xf1[kt].z), "v"(xf1[kt].w));
        union { uint4 u; short8_t s; } cv;
        cv.u = make_uint4(r0, r1, r2, r3);
        a[kt] = cv.s;
    }

    f32x4 accA[4], accB[4];
#pragma unroll
    for (int c = 0; c < 4; c++) {
        accA[c] = (f32x4){0.f, 0.f, 0.f, 0.f};
        accB[c] = (f32x4){0.f, 0.f, 0.f, 0.f};
    }

    const uint4* wg = (const uint4*)Wt;
#pragma unroll
    for (int h = 0; h < 2; h++) {
        if (h) __syncthreads();
#pragma unroll
        for (int i = 0; i < 8; i++) {
            int e = tid + i * 256;
            int lc = e >> 5, ch = e & 31;
            wlds[lc * 32 + (ch ^ (lc & 7))] = wg[(size_t)h * 2048 + e];
        }
        __syncthreads();

        f32x4* acc = h ? accB : accA;
#pragma unroll
        for (int kt = 0; kt < 8; kt++) {
            int ch = kt * 4 + kg;
#pragma unroll
            for (int c = 0; c < 4; c++) {
                int lc = c * 16 + q;
                short8_t bfr = *(const short8_t*)&wlds[lc * 32 + (ch ^ (lc & 7))];
                acc[c] = __builtin_amdgcn_mfma_f32_16x16x32_bf16(a[kt], bfr, acc[c], 0, 0, 0);
            }
        }
    }

#pragma unroll
    for (int i = 0; i < 4; i++) {
        int r = bid * 64 + wid * 16 + kg * 4 + i;
        if (r < M) {
            int lo = 0, hi = 0;
            lo = __builtin_amdgcn_cvt_pk_fp8_f32(accA[0][i], accA[1][i], lo, false);
            lo = __builtin_amdgcn_cvt_pk_fp8_f32(accA[2][i], accA[3][i], lo, true);
            hi = __builtin_amdgcn_cvt_pk_fp8_f32(accB[0][i], accB[1][i], hi, false);
            hi = __builtin_amdgcn_cvt_pk_fp8_f32(accB[2][i], accB[3][i], hi, true);
            *(uint2*)(H8 + (size_t)r * HID + q * 8) = make_uint2((unsigned)lo, (unsigned)hi);
        }
    }
}

// ---------------- per-bucket LDS histogram + scan -> off, cnt, dinv ----------------

__global__ __launch_bounds__(512) void k_cnt(const unsigned* __restrict__ ebkt,
                                             int* __restrict__ bcur, int nbk,
                                             int* __restrict__ off, int* __restrict__ cnt,
                                             float* __restrict__ dinv, int n) {
    __shared__ int lcnt[BKT_SZ];
    __shared__ int lofs[BKT_SZ];
    __shared__ int lbase;
    int b = blockIdx.x, t = threadIdx.x;
    int n0 = b << BKT_SHIFT;
    lcnt[t] = 0;
    __syncthreads();
    int sz = bcur[b];
    const unsigned* ep = ebkt + (size_t)b * CAP;
    for (int e = t; e < sz; e += 512) atomicAdd(&lcnt[ep[e] & 511u], 1);
    __syncthreads();
    if (t == 0) lbase = atomicAdd(&bcur[nbk], sz);
    lofs[t] = lcnt[t];
    __syncthreads();
    for (int o = 1; o < 512; o <<= 1) {
        int u = (t >= o) ? lofs[t - o] : 0;
        __syncthreads();
        lofs[t] += u;
        __syncthreads();
    }
    int node = n0 + t;
    if (node < n) {
        int c = lcnt[t];
        off[node] = lbase + lofs[t] - c;
        cnt[node] = c;
        dinv[node] = rsqrtf((float)(c + 1));
    }
}

// ---------------- per-bucket placement: pack (src, weight) via LDS cursors ----------------

__global__ __launch_bounds__(512) void k_place(const unsigned* __restrict__ ebkt,
                                               const int* __restrict__ bcur,
                                               const int* __restrict__ off,
                                               const float* __restrict__ dinv,
                                               unsigned* __restrict__ eew, int n) {
    __shared__ int curx[BKT_SZ];
    __shared__ float ldin[BKT_SZ];
    int b = blockIdx.x, t = threadIdx.x;
    int n0 = b << BKT_SHIFT;
    int node = n0 + t;
    if (node < n) {
        curx[t] = off[node];
        ldin[t] = dinv[node];
    }
    __syncthreads();
    int sz = bcur[b];
    const unsigned* ep = ebkt + (size_t)b * CAP;
    for (int e = t; e < sz; e += 512) {
        unsigned ed = ep[e];
        int s = (int)(ed >> 9), dl = (int)(ed & 511u);
        float w = dinv[s] * ldin[dl];
        int pos = atomicAdd(&curx[dl], 1);
        eew[pos] = pack_ew(s, w);
    }
}

// ---------------- agg1 + GEMM2 fused: Z8 = fp8( relu(b1 + agg(H8)) @ W2 ) ----------------
// one 16-lane group per node (16 nodes/block); H2 rows staged in LDS (permuted
// fp16 layout), then wave 0 runs the 16-row MFMA gemm2 and stores Z8 directly.

__global__ __launch_bounds__(256) void k_agg1(const unsigned char* __restrict__ H8,
                                              const unsigned* __restrict__ eew,
                                              const int* __restrict__ off,
                                              const int* __restrict__ cnt,
                                              const float* __restrict__ dinv,
                                              const float* __restrict__ b1,
                                              const __half* __restrict__ W2t,
                                              unsigned char* __restrict__ Z8, int n) {
    __shared__ __half h2s[16][136];   // padded: 272 B row stride (2-way bank alias)
    int tid = threadIdx.x;
    int g = tid >> 4, q = tid & 15;
    int node = blockIdx.x * 16 + g;
    int nodec = min(node, n - 1);     // clamp; padding rows never stored
    float di = dinv[nodec];
    int start = off[nodec], ne = cnt[nodec];

    float acc[8];
    {
        uint2 v = *(const uint2*)(H8 + (size_t)nodec * HID + q * 8);
        float wv = di * di;
        f32x2 f;
        f = __builtin_amdgcn_cvt_pk_f32_fp8((int)v.x, false);
        acc[0] = f[0] * wv; acc[1] = f[1] * wv;
        f = __builtin_amdgcn_cvt_pk_f32_fp8((int)v.x, true);
        acc[2] = f[0] * wv; acc[3] = f[1] * wv;
        f = __builtin_amdgcn_cvt_pk_f32_fp8((int)v.y, false);
        acc[4] = f[0] * wv; acc[5] = f[1] * wv;
        f = __builtin_amdgcn_cvt_pk_f32_fp8((int)v.y, true);
        acc[6] = f[0] * wv; acc[7] = f[1] * wv;
    }

#pragma unroll 4
    for (int j = 0; j < ne; ++j) {
        unsigned u = eew[start + j];          // group-uniform broadcast load
        int s = (int)(u >> 15);
        float wv = __uint_as_float((u & 0x7FFFu) << 17);
        uint2 v = *(const uint2*)(H8 + (size_t)s * HID + q * 8);
        f32x2 f;
        f = __builtin_amdgcn_cvt_pk_f32_fp8((int)v.x, false);
        acc[0] = fmaf(f[0], wv, acc[0]); acc[1] = fmaf(f[1], wv, acc[1]);
        f = __builtin_amdgcn_cvt_pk_f32_fp8((int)v.x, true);
        acc[2] = fmaf(f[0], wv, acc[2]); acc[3] = fmaf(f[1], wv, acc[3]);
        f = __builtin_amdgcn_cvt_pk_f32_fp8((int)v.y, false);
        acc[4] = fmaf(f[0], wv, acc[4]); acc[5] = fmaf(f[1], wv, acc[5]);
        f = __builtin_amdgcn_cvt_pk_f32_fp8((int)v.y, true);
        acc[6] = fmaf(f[0], wv, acc[6]); acc[7] = fmaf(f[1], wv, acc[7]);
    }

    float r[8];
#pragma unroll
    for (int i = 0; i < 8; i++) r[i] = fmaxf(acc[i] + b1[i * 16 + q], 0.f);  // feature i*16+q
    __half2 p0 = __floats2half2_rn(r[0], r[1]);
    __half2 p1 = __floats2half2_rn(r[2], r[3]);
    __half2 p2 = __floats2half2_rn(r[4], r[5]);
    __half2 p3 = __floats2half2_rn(r[6], r[7]);
    uint4 o4;
    o4.x = *(unsigned*)&p0; o4.y = *(unsigned*)&p1;
    o4.z = *(unsigned*)&p2; o4.w = *(unsigned*)&p3;
    *(uint4*)&h2s[g][q * 8] = o4;   // permuted fp16 row into LDS
    __syncthreads();

    // ---- gemm2 epilogue (wave 0 only): 16 nodes x 40 classes via MFMA fp16 ----
    if (tid < 64) {
        int qq = tid & 15, kg = tid >> 4;
        half8_t a[4];
#pragma unroll
        for (int kt = 0; kt < 4; kt++)
            a[kt] = *(const half8_t*)&h2s[qq][kt * 32 + kg * 8];

        f32x4 zacc[3];
#pragma unroll
        for (int c = 0; c < 3; c++) zacc[c] = (f32x4){0.f, 0.f, 0.f, 0.f};

#pragma unroll
        for (int c = 0; c < 3; c++) {
            const __half* wc = W2t + (size_t)(c * 16 + qq) * HID + kg * 8;
#pragma unroll
            for (int kt = 0; kt < 4; kt++) {
                half8_t bfr = *(const half8_t*)(wc + kt * 32);
                zacc[c] = __builtin_amdgcn_mfma_f32_16x16x32_f16(a[kt], bfr, zacc[c], 0, 0, 0);
            }
        }

        int rbase = blockIdx.x * 16 + kg * 4;
#pragma unroll
        for (int c = 0; c < 3; c++) {
            int col = c * 16 + qq;
            if (col < NCLS) {
#pragma unroll
                for (int i = 0; i < 4; i++) {
                    int rr = rbase + i;
                    if (rr < n) {
                        int p = __builtin_amdgcn_cvt_pk_fp8_f32(zacc[c][i], zacc[c][i], 0, false);
                        Z8[(size_t)rr * ZPB + col] = (unsigned char)(p & 0xff);
                    }
                }
            }
        }
    }
}

// ---------------- agg2 + bias + log_softmax (fp8 Z, 1 line/gather) ----------------

__global__ __launch_bounds__(256) void k_agg2(const unsigned char* __restrict__ Z8,
                                              const unsigned* __restrict__ eew,
                                              const int* __restrict__ off,
                                              const int* __restrict__ cnt,
                                              const float* __restrict__ dinv,
                                              const float* __restrict__ b2,
                                              float* __restrict__ Out, int n) {
    int tid = threadIdx.x;
    int node = blockIdx.x * 32 + (tid >> 3);
    int l = tid & 7;
    if (node >= n) return;
    float di = dinv[node];
    int start = off[node], ne = cnt[node];

    float acc[8];
    {
        uint2 v = *(const uint2*)(Z8 + (size_t)node * ZPB + l * 8);
        float wv = di * di;
        f32x2 f;
        f = __builtin_amdgcn_cvt_pk_f32_fp8((int)v.x, false);
        acc[0] = f[0] * wv; acc[1] = f[1] * wv;
        f = __builtin_amdgcn_cvt_pk_f32_fp8((int)v.x, true);
        acc[2] = f[0] * wv; acc[3] = f[1] * wv;
        f = __builtin_amdgcn_cvt_pk_f32_fp8((int)v.y, false);
        acc[4] = f[0] * wv; acc[5] = f[1] * wv;
        f = __builtin_amdgcn_cvt_pk_f32_fp8((int)v.y, true);
        acc[6] = f[0] * wv; acc[7] = f[1] * wv;
    }

#pragma unroll 4
    for (int j = 0; j < ne; ++j) {
        unsigned u = eew[start + j];          // group-uniform broadcast load
        int s = (int)(u >> 15);
        float wv = __uint_as_float((u & 0x7FFFu) << 17);
        uint2 v = *(const uint2*)(Z8 + (size_t)s * ZPB + l * 8);
        f32x2 f;
        f = __builtin_amdgcn_cvt_pk_f32_fp8((int)v.x, false);
        acc[0] = fmaf(f[0], wv, acc[0]); acc[1] = fmaf(f[1], wv, acc[1]);
        f = __builtin_amdgcn_cvt_pk_f32_fp8((int)v.x, true);
        acc[2] = fmaf(f[0], wv, acc[2]); acc[3] = fmaf(f[1], wv, acc[3]);
        f = __builtin_amdgcn_cvt_pk_f32_fp8((int)v.y, false);
        acc[4] = fmaf(f[0], wv, acc[4]); acc[5] = fmaf(f[1], wv, acc[5]);
        f = __builtin_amdgcn_cvt_pk_f32_fp8((int)v.y, true);
        acc[6] = fmaf(f[0], wv, acc[6]); acc[7] = fmaf(f[1], wv, acc[7]);
    }

    bool valid = (l < 5);
    float v[8];
    float m = -INFINITY;
#pragma unroll
    for (int i = 0; i < 8; i++) {
        v[i] = valid ? acc[i] + b2[l * 8 + i] : -INFINITY;
        m = fmaxf(m, v[i]);
    }
#pragma unroll
    for (int o = 1; o <= 4; o <<= 1) m = fmaxf(m, __shfl_xor(m, o));
    float ssum = 0.f;
#pragma unroll
    for (int i = 0; i < 8; i++)
        if (valid) ssum += __expf(v[i] - m);
#pragma unroll
    for (int o = 1; o <= 4; o <<= 1) ssum += __shfl_xor(ssum, o);
    float lse = m + logf(ssum);

    if (valid) {
        float4 w0 = make_float4(v[0] - lse, v[1] - lse, v[2] - lse, v[3] - lse);
        float4 w1 = make_float4(v[4] - lse, v[5] - lse, v[6] - lse, v[7] - lse);
        float* op = Out + (size_t)node * NCLS + l * 8;
        *(float4*)op = w0;
        *(float4*)(op + 4) = w1;
    }
}

// ---------------- launch ----------------

extern "C" void kernel_launch(void* const* d_in, const int* in_sizes, int n_in,
                              void* d_out, int out_size, void* d_ws, size_t ws_size,
                              hipStream_t stream) {
    const float* x  = (const float*)d_in[0];
    const int* ei   = (const int*)d_in[1];
    const float* W1 = (const float*)d_in[2];
    const float* b1 = (const float*)d_in[3];
    const float* W2 = (const float*)d_in[4];
    const float* b2 = (const float*)d_in[5];
    float* out = (float*)d_out;

    const int n = in_sizes[0] / FIN;   // 100000
    const int E = in_sizes[1] / 2;     // 1600000
    const int* src = ei;
    const int* dst = ei + E;
    const int nbk = (n + BKT_SZ - 1) >> BKT_SHIFT;  // 196

    char* w = (char*)d_ws;
    auto alloc = [&](size_t bytes) {
        char* p = w;
        w += (bytes + 255) & ~(size_t)255;
        return p;
    };
    int* off     = (int*)alloc((size_t)n * 4);
    int* cnt     = (int*)alloc((size_t)n * 4);
    float* dinv  = (float*)alloc((size_t)n * 4);
    int* bcur    = (int*)alloc((size_t)(nbk + 1) * 4);  // +1: global base ticket
    unsigned* ebkt = (unsigned*)alloc((size_t)nbk * CAP * 4);
    unsigned* eew  = (unsigned*)alloc((size_t)E * 4);
    ushort* wt   = (ushort*)alloc((size_t)FIN * HID * 2);
    __half* w2t  = (__half*)alloc((size_t)48 * HID * 2);
    unsigned char* H8 = (unsigned char*)alloc((size_t)n * HID);
    unsigned char* Z8 = (unsigned char*)alloc((size_t)n * ZPB);

    const int nbkb = (E + CHUNK - 1) / CHUNK;        // bucketize blocks (782)
    const int g1b = (n + 63) / 64;                   // gemm1 blocks (1563)

    // prep: zero bucket cursors + ticket + convert both weight matrices
    k_prep<<<(FIN * HID) / 256, 256, 0, stream>>>(bcur, W1, wt, W2, w2t, nbk);

    // fused + interleaved: bucketize co-scheduled with half-tiled gemm1
    k_g1bkt<<<nbkb + g1b, 256, 0, stream>>>(x, wt, H8, n, src, dst, E, bcur, ebkt, nbk, nbkb);

    // CSR finalize, bucket-local
    k_cnt<<<nbk, 512, 0, stream>>>(ebkt, bcur, nbk, off, cnt, dinv, n);
    k_place<<<nbk, 512, 0, stream>>>(ebkt, bcur, off, dinv, eew, n);

    // layer 1 aggregation + fused GEMM2
    k_agg1<<<(n + 15) / 16, 256, 0, stream>>>(H8, eew, off, cnt, dinv, b1, w2t, Z8, n);

    // layer 2 aggregation + log_softmax
    k_agg2<<<(n + 31) / 32, 256, 0, stream>>>(Z8, eew, off, cnt, dinv, b2, out, n);
}